// Round 4
// baseline (490.561 us; speedup 1.0000x reference)
//
#include <hip/hip_runtime.h>

#define DI __device__ __forceinline__

typedef __attribute__((ext_vector_type(8))) short bf16x8;
typedef __attribute__((ext_vector_type(4))) float f32x4;
typedef __attribute__((address_space(1))) const unsigned char GAS;
typedef __attribute__((address_space(3))) unsigned char LAS;

DI unsigned short f2bf(float x) {
  unsigned int u = __builtin_bit_cast(unsigned int, x);
  u = u + 0x7fffu + ((u >> 16) & 1u);
  return (unsigned short)(u >> 16);
}
DI float bf2f(unsigned short h) {
  unsigned int u = ((unsigned int)h) << 16;
  return __builtin_bit_cast(float, u);
}

// ---------------- K1: prep — convert X to bf16, transpose W (3x), convert E ----------
__global__ __launch_bounds__(256) void prep_kernel(
    const float* __restrict__ hs, const float* __restrict__ Wq,
    const float* __restrict__ Wk, const float* __restrict__ Wv,
    const float* __restrict__ de,
    unsigned short* __restrict__ Xb,   // [4096][768] bf16
    unsigned short* __restrict__ Wt,   // [2304 n][768 k] bf16 (q,k,v stacked)
    unsigned short* __restrict__ Eb)   // [2048][64] bf16 (row 2047 zero)
{
  const int bid = blockIdx.x, t = threadIdx.x;
  __shared__ unsigned short wlds[64 * 68];
  if (bid < 1536) {
    size_t base = (size_t)bid * 2048 + (size_t)t * 8;
    float4 a = *(const float4*)(hs + base);
    float4 b = *(const float4*)(hs + base + 4);
    union { unsigned short u[8]; uint4 v; } pk;
    pk.u[0]=f2bf(a.x); pk.u[1]=f2bf(a.y); pk.u[2]=f2bf(a.z); pk.u[3]=f2bf(a.w);
    pk.u[4]=f2bf(b.x); pk.u[5]=f2bf(b.y); pk.u[6]=f2bf(b.z); pk.u[7]=f2bf(b.w);
    *(uint4*)(Xb + base) = pk.v;
  } else if (bid < 1968) {
    int q = bid - 1536;
    int wi = q / 144, tile = q % 144;
    int tr = tile / 12, tc = tile % 12;
    int k0 = tr * 64, n0 = tc * 64;
    const float* W = wi == 0 ? Wq : (wi == 1 ? Wk : Wv);
    int i = t >> 2, cb = (t & 3) * 16;
    const float* src = W + (size_t)(k0 + i) * 768 + n0 + cb;
#pragma unroll
    for (int c4 = 0; c4 < 4; ++c4) {
      float4 v = *(const float4*)(src + c4 * 4);
      wlds[i * 68 + cb + c4 * 4 + 0] = f2bf(v.x);
      wlds[i * 68 + cb + c4 * 4 + 1] = f2bf(v.y);
      wlds[i * 68 + cb + c4 * 4 + 2] = f2bf(v.z);
      wlds[i * 68 + cb + c4 * 4 + 3] = f2bf(v.w);
    }
    __syncthreads();
    int n = t >> 2, ks = (t & 3) * 16;
    union { unsigned short u[16]; uint4 v[2]; } pk;
#pragma unroll
    for (int e = 0; e < 16; ++e) pk.u[e] = wlds[(ks + e) * 68 + n];
    unsigned short* dst = Wt + (size_t)wi * 589824 + (size_t)(n0 + n) * 768 + k0 + ks;
    *(uint4*)(dst) = pk.v[0];
    *(uint4*)(dst + 8) = pk.v[1];
  } else {
    int q = bid - 1968;
    size_t base = (size_t)q * 2048 + (size_t)t * 8;
    union { unsigned short u[8]; uint4 v; } pk;
    if (base < 131008) {
      float4 a = *(const float4*)(de + base);
      float4 b = *(const float4*)(de + base + 4);
      pk.u[0]=f2bf(a.x); pk.u[1]=f2bf(a.y); pk.u[2]=f2bf(a.z); pk.u[3]=f2bf(a.w);
      pk.u[4]=f2bf(b.x); pk.u[5]=f2bf(b.y); pk.u[6]=f2bf(b.z); pk.u[7]=f2bf(b.w);
    } else {
      pk.v = uint4{0u, 0u, 0u, 0u};
    }
    *(uint4*)(Eb + base) = pk.v;
  }
}

// ---------------- K2: fused QKV GEMM [4096 x 2304 x 768], 128x128 tile, gload_lds ----
__global__ __launch_bounds__(256) void proj_kernel(
    const unsigned short* __restrict__ Xb, const unsigned short* __restrict__ Wt,
    const float* __restrict__ bq, const float* __restrict__ bk, const float* __restrict__ bv,
    unsigned short* __restrict__ Qb, unsigned short* __restrict__ Kb,
    unsigned short* __restrict__ Vb)
{
  const int x = blockIdx.x, y = blockIdx.y;
  const int t = threadIdx.x, w = t >> 6, lane = t & 63, g = lane >> 4, ln = lane & 15;
  const int wm = w >> 1, wn = w & 1;
  __shared__ __align__(16) unsigned char smem[32768];
  unsigned char* sA = smem;          // [128 m][128B k] swizzled
  unsigned char* sB = smem + 16384;  // [128 n][128B k] swizzled
  const int m0 = x * 128, n0 = y * 128;
  const int sec = y / 6, hb = (y % 6) * 2 + wn;
  const float* bias = sec == 0 ? bq : (sec == 1 ? bk : bv);
  unsigned short* Out = sec == 0 ? Qb : (sec == 1 ? Kb : Vb);
  const unsigned char* Xbb = (const unsigned char*)Xb;
  const unsigned char* Wtb = (const unsigned char*)Wt;

  f32x4 acc[4][4];
#pragma unroll
  for (int a = 0; a < 4; ++a)
#pragma unroll
    for (int c = 0; c < 4; ++c) acc[a][c] = f32x4{0.f, 0.f, 0.f, 0.f};

  for (int kt = 0; kt < 12; ++kt) {
    __syncthreads();
#pragma unroll
    for (int ci = 0; ci < 4; ++ci) {
      int idx = ci * 1024 + lane * 16;
      int rl = idx >> 7, col = idx & 127;
      int row = w * 32 + rl;
      int scol = col ^ ((row & 7) << 4);
      __builtin_amdgcn_global_load_lds(
          (const GAS*)(Xbb + (size_t)(m0 + row) * 1536 + kt * 128 + scol),
          (LAS*)(sA + w * 4096 + ci * 1024), 16, 0, 0);
      __builtin_amdgcn_global_load_lds(
          (const GAS*)(Wtb + (size_t)(n0 + row) * 1536 + kt * 128 + scol),
          (LAS*)(sB + w * 4096 + ci * 1024), 16, 0, 0);
    }
    __syncthreads();
    bf16x8 af[4][2], bfr[4][2];
#pragma unroll
    for (int ms = 0; ms < 4; ++ms) {
      int row = wm * 64 + ms * 16 + ln;
#pragma unroll
      for (int ks = 0; ks < 2; ++ks)
        af[ms][ks] = *(const bf16x8*)(sA + ((row * 128 + ks * 64 + g * 16) ^ ((row & 7) << 4)));
    }
#pragma unroll
    for (int c = 0; c < 4; ++c) {
      int row = wn * 64 + c * 16 + ln;
#pragma unroll
      for (int ks = 0; ks < 2; ++ks)
        bfr[c][ks] = *(const bf16x8*)(sB + ((row * 128 + ks * 64 + g * 16) ^ ((row & 7) << 4)));
    }
#pragma unroll
    for (int ms = 0; ms < 4; ++ms)
#pragma unroll
      for (int c = 0; c < 4; ++c) {
        acc[ms][c] = __builtin_amdgcn_mfma_f32_16x16x32_bf16(af[ms][0], bfr[c][0], acc[ms][c], 0, 0, 0);
        acc[ms][c] = __builtin_amdgcn_mfma_f32_16x16x32_bf16(af[ms][1], bfr[c][1], acc[ms][c], 0, 0, 0);
      }
  }
  float b4[4];
#pragma unroll
  for (int c = 0; c < 4; ++c) b4[c] = bias[hb * 64 + c * 16 + ln];
#pragma unroll
  for (int ms = 0; ms < 4; ++ms)
#pragma unroll
    for (int c = 0; c < 4; ++c)
#pragma unroll
      for (int jj = 0; jj < 4; ++jj) {
        int m = m0 + wm * 64 + ms * 16 + g * 4 + jj;
        int bb = m >> 10, s = m & 1023;
        float v = acc[ms][c][jj] + b4[c];
        Out[((size_t)(bb * 12 + hb) * 1024 + s) * 64 + c * 16 + ln] = f2bf(v);
      }
}

// ---------------- K3: V -> V^T  ([bh][s][d] -> [bh][d][s]) ---------------------------
__global__ __launch_bounds__(256) void vtrans_kernel(
    const unsigned short* __restrict__ Vb, unsigned short* __restrict__ Vtb)
{
  const int s0 = blockIdx.x * 256, bh = blockIdx.y, t = threadIdx.x;
  __shared__ __align__(16) unsigned short lds[256 * 64];
  const unsigned short* src = Vb + ((size_t)bh * 1024 + s0 + t) * 64;
#pragma unroll
  for (int gi = 0; gi < 8; ++gi) {
    uint4 v = *(const uint4*)(src + gi * 8);
    *(uint4*)((unsigned char*)lds + t * 128 + ((gi ^ (t & 7)) << 4)) = v;
  }
  __syncthreads();
  const int d = t >> 2, seg = t & 3;
  unsigned short* dst = Vtb + ((size_t)bh * 64 + d) * 1024 + s0 + seg * 64;
#pragma unroll
  for (int ck = 0; ck < 8; ++ck) {
    union { unsigned short u[8]; uint4 v; } pk;
#pragma unroll
    for (int e = 0; e < 8; ++e) {
      int sl = seg * 64 + ck * 8 + e;
      pk.u[e] = lds[sl * 64 + (((d >> 3) ^ (sl & 7)) << 3) + (d & 7)];
    }
    *(uint4*)(dst + ck * 8) = pk.v;
  }
}

// ---------------- K4: fused attention (split-r 2-way) --------------------------------
// LDS: sK 8192 | Ht [128][68] 17408 | per-wave Gt[80][20] overlaid with P[16][64] 4x3264
__global__ __launch_bounds__(256, 3) void attn_kernel(
    const float* __restrict__ amask, const float* __restrict__ rmask,
    const unsigned short* __restrict__ Qb, const unsigned short* __restrict__ Kb,
    const unsigned short* __restrict__ Vtb, const unsigned short* __restrict__ Eb,
    float* __restrict__ pctx, float* __restrict__ pm)
{
  const int h = blockIdx.x, yy = blockIdx.y, b = blockIdx.z;
  const int lb = yy >> 1, half = yy & 1;
  const int bh = b * 12 + h, l0 = lb * 64;
  const int t = threadIdx.x, w = t >> 6, lane = t & 63, g = lane >> 4, ln = lane & 15;
  __shared__ __align__(16) unsigned char smem[38656];
  unsigned char* sK = smem;                                   // [64 r][64 k] swz
  unsigned short* Ht = (unsigned short*)(smem + 8192);        // [128 j][68 r-cols]
  unsigned short* Gtw = (unsigned short*)(smem + 25600 + w * 3264);  // [80 jl][20 l-cols]
  unsigned char* Pw = (unsigned char*)Gtw;                    // overlay: [16 l][64 r] swz

  const unsigned short* Qrow = Qb + ((size_t)bh * 1024 + l0 + w * 16 + ln) * 64;
  const bf16x8 qa0 = *(const bf16x8*)(Qrow + g * 8);
  const bf16x8 qa1 = *(const bf16x8*)(Qrow + 32 + g * 8);

  f32x4 ctx[4];
#pragma unroll
  for (int c = 0; c < 4; ++c) ctx[c] = f32x4{0.f, 0.f, 0.f, 0.f};
  float mrun[4] = {-1e30f, -1e30f, -1e30f, -1e30f};
  float sig[4] = {0.f, 0.f, 0.f, 0.f};

  const unsigned char* Kbase = (const unsigned char*)(Kb + (size_t)bh * 65536);
  const unsigned char* Vbase = (const unsigned char*)Vtb;
  const int itBeg = half * 8, itEnd = itBeg + 8;

  uint4 kp[2];
#pragma unroll
  for (int i = 0; i < 2; ++i) {
    int p = i * 4096 + t * 16, row = p >> 7, col = p & 127;
    kp[i] = *(const uint4*)(Kbase + (size_t)(itBeg * 64 + row) * 128 + col);
  }

  for (int it = itBeg; it < itEnd; ++it) {
    const int r0 = it * 64;
    __syncthreads();
    // stage K tile (swizzled)
#pragma unroll
    for (int i = 0; i < 2; ++i) {
      int p = i * 4096 + t * 16, row = p >> 7;
      *(uint4*)(sK + (p ^ ((row & 7) << 4))) = kp[i];
    }
    // prefetch next K tile
    if (it + 1 < itEnd) {
#pragma unroll
      for (int i = 0; i < 2; ++i) {
        int p = i * 4096 + t * 16, row = p >> 7, col = p & 127;
        kp[i] = *(const uint4*)(Kbase + (size_t)(r0 + 64 + row) * 128 + col);
      }
    }
    // prefetch current-tile rmask (consumed in softmax, far below)
    float rmf[4][4];
    const float* rbase = rmask + (size_t)b * 1048576 + (size_t)(l0 + w * 16 + g * 4) * 1024 + r0;
#pragma unroll
    for (int jj = 0; jj < 4; ++jj)
#pragma unroll
      for (int ct = 0; ct < 4; ++ct)
        rmf[ct][jj] = rbase[(size_t)jj * 1024 + ct * 16 + ln];
    // prefetch current-tile V fragments (consumed in PV at the very end)
    uint4 vfr[4][2];
#pragma unroll
    for (int cd = 0; cd < 4; ++cd)
#pragma unroll
      for (int ks = 0; ks < 2; ++ks)
        vfr[cd][ks] = *(const uint4*)(Vbase +
            ((size_t)(bh * 64 + cd * 16 + ln) * 1024 + r0 + ks * 32 + g * 8) * 2);
    float am4[4];
#pragma unroll
    for (int ct = 0; ct < 4; ++ct)
      am4[ct] = amask[b * 1024 + r0 + ct * 16 + ln] * 1.4426950408889634f;

    // ---- G phase (wave-private): G[l][j] = q[l].E[D0+j], j-window [w16, w16+80)
    const int D0 = l0 - r0 + 960;
#pragma unroll
    for (int cc = 0; cc < 5; ++cc) {
      int c = w + cc;
      const unsigned short* Erow = Eb + (size_t)(D0 + c * 16 + ln) * 64;
      bf16x8 e0 = *(const bf16x8*)(Erow + g * 8);
      bf16x8 e1 = *(const bf16x8*)(Erow + 32 + g * 8);
      f32x4 ga = f32x4{0.f, 0.f, 0.f, 0.f};
      ga = __builtin_amdgcn_mfma_f32_16x16x32_bf16(qa0, e0, ga, 0, 0, 0);
      ga = __builtin_amdgcn_mfma_f32_16x16x32_bf16(qa1, e1, ga, 0, 0, 0);
      ushort4 pk = {f2bf(ga[0]), f2bf(ga[1]), f2bf(ga[2]), f2bf(ga[3])};
      *(ushort4*)(Gtw + (cc * 16 + ln) * 20 + g * 4) = pk;
    }
    __syncthreads();  // sK visible to all waves
    // QK fragments + H A-operand
    bf16x8 kb[4][2];
#pragma unroll
    for (int c = 0; c < 4; ++c)
#pragma unroll
      for (int ks = 0; ks < 2; ++ks) {
        int row = c * 16 + ln;
        kb[c][ks] = *(const bf16x8*)(sK + ((row * 128 + ks * 64 + g * 16) ^ ((row & 7) << 4)));
      }
    bf16x8 ha0, ha1;
    {
      int row = w * 16 + ln;
      ha0 = *(const bf16x8*)(sK + ((row * 128 + g * 16) ^ ((row & 7) << 4)));
      ha1 = *(const bf16x8*)(sK + ((row * 128 + 64 + g * 16) ^ ((row & 7) << 4)));
    }
    // ---- H phase: H[r][j] = k[r].E[D0+j]; own r-rows, j-window [48-w16, 127-w16]
#pragma unroll
    for (int cc = 0; cc < 5; ++cc) {
      int c = 3 - w + cc;
      const unsigned short* Erow = Eb + (size_t)(D0 + c * 16 + ln) * 64;
      bf16x8 e0 = *(const bf16x8*)(Erow + g * 8);
      bf16x8 e1 = *(const bf16x8*)(Erow + 32 + g * 8);
      f32x4 hac = f32x4{0.f, 0.f, 0.f, 0.f};
      hac = __builtin_amdgcn_mfma_f32_16x16x32_bf16(ha0, e0, hac, 0, 0, 0);
      hac = __builtin_amdgcn_mfma_f32_16x16x32_bf16(ha1, e1, hac, 0, 0, 0);
      ushort4 pk = {f2bf(hac[0]), f2bf(hac[1]), f2bf(hac[2]), f2bf(hac[3])};
      *(ushort4*)(Ht + (size_t)(c * 16 + ln) * 68 + w * 16 + g * 4) = pk;
    }
    __syncthreads();  // Ht visible
    // ---- bias gather into C, then QK^T accumulates on top
    f32x4 sacc[4];
#pragma unroll
    for (int ct = 0; ct < 4; ++ct) {
      int rlb = ct * 16 + ln;
      f32x4 si;
#pragma unroll
      for (int jj = 0; jj < 4; ++jj) {
        int lloc = g * 4 + jj;
        int j = w * 16 + lloc - rlb + 63;
        si[jj] = bf2f(Gtw[(lloc - rlb + 63) * 20 + lloc]) + bf2f(Ht[(size_t)j * 68 + rlb]);
      }
      sacc[ct] = si;
      sacc[ct] = __builtin_amdgcn_mfma_f32_16x16x32_bf16(qa0, kb[ct][0], sacc[ct], 0, 0, 0);
      sacc[ct] = __builtin_amdgcn_mfma_f32_16x16x32_bf16(qa1, kb[ct][1], sacc[ct], 0, 0, 0);
    }
    // ---- online softmax (log2 domain), mask as multiplier
    float sv[4][4], rmax[4];
#pragma unroll
    for (int jj = 0; jj < 4; ++jj) {
#pragma unroll
      for (int ct = 0; ct < 4; ++ct) sv[ct][jj] = sacc[ct][jj] * 0.1803368801f + am4[ct];
      float rv = fmaxf(fmaxf(sv[0][jj], sv[1][jj]), fmaxf(sv[2][jj], sv[3][jj]));
#pragma unroll
      for (int mm = 1; mm < 16; mm <<= 1) rv = fmaxf(rv, __shfl_xor(rv, mm));
      rmax[jj] = rv;
    }
    float sf[4], mnew[4];
#pragma unroll
    for (int jj = 0; jj < 4; ++jj) {
      mnew[jj] = fmaxf(mrun[jj], rmax[jj]);
      sf[jj] = __builtin_amdgcn_exp2f(mrun[jj] - mnew[jj]);
      mrun[jj] = mnew[jj];
    }
    float rs[4] = {0.f, 0.f, 0.f, 0.f};
    unsigned short pb[4][4];
#pragma unroll
    for (int ct = 0; ct < 4; ++ct)
#pragma unroll
      for (int jj = 0; jj < 4; ++jj) {
        float mv = fmaxf(rmf[ct][jj], 1e-5f);
        float p = mv * __builtin_amdgcn_exp2f(sv[ct][jj] - mnew[jj]);
        rs[jj] += p;
        pb[ct][jj] = f2bf(p);
      }
#pragma unroll
    for (int jj = 0; jj < 4; ++jj) {
      float rv = rs[jj];
#pragma unroll
      for (int mm = 1; mm < 16; mm <<= 1) rv += __shfl_xor(rv, mm);
      sig[jj] = sig[jj] * sf[jj] + rv;
    }
#pragma unroll
    for (int c = 0; c < 4; ++c)
#pragma unroll
      for (int jj = 0; jj < 4; ++jj) ctx[c][jj] *= sf[jj];
    // ---- P -> wave-private LDS (overlaid on Gt; ordered by data dependence)
#pragma unroll
    for (int ct = 0; ct < 4; ++ct)
#pragma unroll
      for (int jj = 0; jj < 4; ++jj) {
        int lp = g * 4 + jj;
        *(unsigned short*)(Pw + ((lp * 128 + (ct * 16 + ln) * 2) ^ ((lp & 7) << 4))) = pb[ct][jj];
      }
    bf16x8 pa0, pa1;
    {
      int lr = ln;
      pa0 = *(const bf16x8*)(Pw + ((lr * 128 + g * 16) ^ ((lr & 7) << 4)));
      pa1 = *(const bf16x8*)(Pw + ((lr * 128 + 64 + g * 16) ^ ((lr & 7) << 4)));
    }
    // ---- PV with prefetched V fragments
#pragma unroll
    for (int cd = 0; cd < 4; ++cd) {
      bf16x8 v0 = __builtin_bit_cast(bf16x8, vfr[cd][0]);
      bf16x8 v1 = __builtin_bit_cast(bf16x8, vfr[cd][1]);
      ctx[cd] = __builtin_amdgcn_mfma_f32_16x16x32_bf16(pa0, v0, ctx[cd], 0, 0, 0);
      ctx[cd] = __builtin_amdgcn_mfma_f32_16x16x32_bf16(pa1, v1, ctx[cd], 0, 0, 0);
    }
  }
  // ---- write partials
  const size_t rowb = (size_t)(half * 48 + bh) * 1024 + l0 + w * 16;
#pragma unroll
  for (int cd = 0; cd < 4; ++cd)
#pragma unroll
    for (int jj = 0; jj < 4; ++jj)
      pctx[(rowb + g * 4 + jj) * 64 + cd * 16 + ln] = ctx[cd][jj];
  if (ln == 0) {
#pragma unroll
    for (int jj = 0; jj < 4; ++jj) {
      size_t rr = rowb + g * 4 + jj;
      pm[rr * 2] = mrun[jj];
      pm[rr * 2 + 1] = sig[jj];
    }
  }
}

// ---------------- K5: combine the two r-halves ---------------------------------------
__global__ __launch_bounds__(256) void combine_kernel(
    const float* __restrict__ pctx, const float* __restrict__ pm,
    float* __restrict__ out)
{
  int tid = blockIdx.x * 256 + threadIdx.x;
  int row = tid >> 4, dq = (tid & 15) * 4;
  int bh = row >> 10, l = row & 1023, b = bh / 12, hh = bh % 12;
  float m0 = pm[(size_t)row * 2], s0 = pm[(size_t)row * 2 + 1];
  float m1 = pm[(size_t)(49152 + row) * 2], s1 = pm[(size_t)(49152 + row) * 2 + 1];
  float M = fmaxf(m0, m1);
  float w0 = __builtin_amdgcn_exp2f(m0 - M), w1 = __builtin_amdgcn_exp2f(m1 - M);
  float inv = 1.f / (s0 * w0 + s1 * w1);
  float4 c0 = *(const float4*)(pctx + (size_t)row * 64 + dq);
  float4 c1 = *(const float4*)(pctx + (size_t)(49152 + row) * 64 + dq);
  float4 o;
  o.x = (c0.x * w0 + c1.x * w1) * inv;
  o.y = (c0.y * w0 + c1.y * w1) * inv;
  o.z = (c0.z * w0 + c1.z * w1) * inv;
  o.w = (c0.w * w0 + c1.w * w1) * inv;
  *(float4*)(out + (size_t)(b * 1024 + l) * 768 + hh * 64 + dq) = o;
}

extern "C" void kernel_launch(void* const* d_in, const int* in_sizes, int n_in,
                              void* d_out, int out_size, void* d_ws, size_t ws_size,
                              hipStream_t stream) {
  const float* hs    = (const float*)d_in[0];
  const float* amask = (const float*)d_in[1];
  const float* rmask = (const float*)d_in[2];
  const float* Wq    = (const float*)d_in[3];
  const float* bq    = (const float*)d_in[4];
  const float* Wk    = (const float*)d_in[5];
  const float* bk    = (const float*)d_in[6];
  const float* Wv    = (const float*)d_in[7];
  const float* bv    = (const float*)d_in[8];
  const float* de    = (const float*)d_in[9];
  unsigned char* ws = (unsigned char*)d_ws;
  unsigned short* Xb  = (unsigned short*)(ws + 0);         // 6291456 B
  unsigned short* Wt  = (unsigned short*)(ws + 6291456);   // 3538944 B
  unsigned short* Eb  = (unsigned short*)(ws + 9830400);   // 262144 B
  unsigned short* Qb  = (unsigned short*)(ws + 10092544);  // 6291456 B
  unsigned short* Kb  = (unsigned short*)(ws + 16384000);  // 6291456 B
  unsigned short* Vb  = (unsigned short*)(ws + 22675456);  // 6291456 B
  unsigned short* Vtb = (unsigned short*)(ws + 28966912);  // 6291456 B
  float* pctx = (float*)(ws + 35258368);                   // 25165824 B
  float* pm   = (float*)(ws + 60424192);                   // 786432 B  (total 61.2 MB)
  float* out = (float*)d_out;

  hipLaunchKernelGGL(prep_kernel, dim3(2032), dim3(256), 0, stream,
                     hs, Wq, Wk, Wv, de, Xb, Wt, Eb);
  hipLaunchKernelGGL(proj_kernel, dim3(32, 18), dim3(256), 0, stream,
                     Xb, Wt, bq, bk, bv, Qb, Kb, Vb);
  hipLaunchKernelGGL(vtrans_kernel, dim3(4, 48), dim3(256), 0, stream, Vb, Vtb);
  hipLaunchKernelGGL(attn_kernel, dim3(12, 32, 4), dim3(256), 0, stream,
                     amask, rmask, Qb, Kb, Vtb, Eb, pctx, pm);
  hipLaunchKernelGGL(combine_kernel, dim3(3072), dim3(256), 0, stream, pctx, pm, out);
}

// Round 5
// 314.992 us; speedup vs baseline: 1.5574x; 1.5574x over previous
//
#include <hip/hip_runtime.h>

#define DI __device__ __forceinline__

typedef __attribute__((ext_vector_type(8))) short bf16x8;
typedef __attribute__((ext_vector_type(4))) float f32x4;
typedef __attribute__((address_space(1))) const unsigned char GAS;
typedef __attribute__((address_space(3))) unsigned char LAS;

DI unsigned short f2bf(float x) {
  unsigned int u = __builtin_bit_cast(unsigned int, x);
  u = u + 0x7fffu + ((u >> 16) & 1u);
  return (unsigned short)(u >> 16);
}
DI float bf2f(unsigned short h) {
  unsigned int u = ((unsigned int)h) << 16;
  return __builtin_bit_cast(float, u);
}

// ---------------- K1: prep — X->bf16, W^T (3x), E->bf16, Lm = log2(clip(rmask)) fp16 -
__global__ __launch_bounds__(256) void prep_kernel(
    const float* __restrict__ hs, const float* __restrict__ Wq,
    const float* __restrict__ Wk, const float* __restrict__ Wv,
    const float* __restrict__ de, const float* __restrict__ rmask,
    unsigned short* __restrict__ Xb,   // [4096][768] bf16
    unsigned short* __restrict__ Wt,   // [2304 n][768 k] bf16 (q,k,v stacked)
    unsigned short* __restrict__ Eb,   // [2048][64] bf16 (row 2047 zero)
    _Float16* __restrict__ Lm)         // [4][1024 l][1024 r] fp16 log2-mask
{
  const int bid = blockIdx.x, t = threadIdx.x;
  __shared__ unsigned short wlds[64 * 68];
  if (bid < 1536) {
    size_t base = (size_t)bid * 2048 + (size_t)t * 8;
    float4 a = *(const float4*)(hs + base);
    float4 b = *(const float4*)(hs + base + 4);
    union { unsigned short u[8]; uint4 v; } pk;
    pk.u[0]=f2bf(a.x); pk.u[1]=f2bf(a.y); pk.u[2]=f2bf(a.z); pk.u[3]=f2bf(a.w);
    pk.u[4]=f2bf(b.x); pk.u[5]=f2bf(b.y); pk.u[6]=f2bf(b.z); pk.u[7]=f2bf(b.w);
    *(uint4*)(Xb + base) = pk.v;
  } else if (bid < 1968) {
    int q = bid - 1536;
    int wi = q / 144, tile = q % 144;
    int tr = tile / 12, tc = tile % 12;
    int k0 = tr * 64, n0 = tc * 64;
    const float* W = wi == 0 ? Wq : (wi == 1 ? Wk : Wv);
    int i = t >> 2, cb = (t & 3) * 16;
    const float* src = W + (size_t)(k0 + i) * 768 + n0 + cb;
#pragma unroll
    for (int c4 = 0; c4 < 4; ++c4) {
      float4 v = *(const float4*)(src + c4 * 4);
      wlds[i * 68 + cb + c4 * 4 + 0] = f2bf(v.x);
      wlds[i * 68 + cb + c4 * 4 + 1] = f2bf(v.y);
      wlds[i * 68 + cb + c4 * 4 + 2] = f2bf(v.z);
      wlds[i * 68 + cb + c4 * 4 + 3] = f2bf(v.w);
    }
    __syncthreads();
    int n = t >> 2, ks = (t & 3) * 16;
    union { unsigned short u[16]; uint4 v[2]; } pk;
#pragma unroll
    for (int e = 0; e < 16; ++e) pk.u[e] = wlds[(ks + e) * 68 + n];
    unsigned short* dst = Wt + (size_t)wi * 589824 + (size_t)(n0 + n) * 768 + k0 + ks;
    *(uint4*)(dst) = pk.v[0];
    *(uint4*)(dst + 8) = pk.v[1];
  } else if (bid < 2032) {
    int q = bid - 1968;
    size_t base = (size_t)q * 2048 + (size_t)t * 8;
    union { unsigned short u[8]; uint4 v; } pk;
    if (base < 131008) {
      float4 a = *(const float4*)(de + base);
      float4 b = *(const float4*)(de + base + 4);
      pk.u[0]=f2bf(a.x); pk.u[1]=f2bf(a.y); pk.u[2]=f2bf(a.z); pk.u[3]=f2bf(a.w);
      pk.u[4]=f2bf(b.x); pk.u[5]=f2bf(b.y); pk.u[6]=f2bf(b.z); pk.u[7]=f2bf(b.w);
    } else {
      pk.v = uint4{0u, 0u, 0u, 0u};
    }
    *(uint4*)(Eb + base) = pk.v;
  } else {
    int q = bid - 2032;  // 0..2047
    size_t base = (size_t)q * 2048 + (size_t)t * 8;
    float4 a = *(const float4*)(rmask + base);
    float4 b = *(const float4*)(rmask + base + 4);
    union { _Float16 h[8]; uint4 v; } pk;
    pk.h[0] = (_Float16)__log2f(fmaxf(a.x, 1e-5f));
    pk.h[1] = (_Float16)__log2f(fmaxf(a.y, 1e-5f));
    pk.h[2] = (_Float16)__log2f(fmaxf(a.z, 1e-5f));
    pk.h[3] = (_Float16)__log2f(fmaxf(a.w, 1e-5f));
    pk.h[4] = (_Float16)__log2f(fmaxf(b.x, 1e-5f));
    pk.h[5] = (_Float16)__log2f(fmaxf(b.y, 1e-5f));
    pk.h[6] = (_Float16)__log2f(fmaxf(b.z, 1e-5f));
    pk.h[7] = (_Float16)__log2f(fmaxf(b.w, 1e-5f));
    *(uint4*)(Lm + base) = pk.v;
  }
}

// ---------------- K2: fused QKV GEMM [4096 x 2304 x 768], 128x128 tile, gload_lds ----
__global__ __launch_bounds__(256) void proj_kernel(
    const unsigned short* __restrict__ Xb, const unsigned short* __restrict__ Wt,
    const float* __restrict__ bq, const float* __restrict__ bk, const float* __restrict__ bv,
    unsigned short* __restrict__ Qb, unsigned short* __restrict__ Kb,
    unsigned short* __restrict__ Vb)
{
  const int x = blockIdx.x, y = blockIdx.y;
  const int t = threadIdx.x, w = t >> 6, lane = t & 63, g = lane >> 4, ln = lane & 15;
  const int wm = w >> 1, wn = w & 1;
  __shared__ __align__(16) unsigned char smem[32768];
  unsigned char* sA = smem;          // [128 m][128B k] swizzled
  unsigned char* sB = smem + 16384;  // [128 n][128B k] swizzled
  const int m0 = x * 128, n0 = y * 128;
  const int sec = y / 6, hb = (y % 6) * 2 + wn;
  const float* bias = sec == 0 ? bq : (sec == 1 ? bk : bv);
  unsigned short* Out = sec == 0 ? Qb : (sec == 1 ? Kb : Vb);
  const unsigned char* Xbb = (const unsigned char*)Xb;
  const unsigned char* Wtb = (const unsigned char*)Wt;

  f32x4 acc[4][4];
#pragma unroll
  for (int a = 0; a < 4; ++a)
#pragma unroll
    for (int c = 0; c < 4; ++c) acc[a][c] = f32x4{0.f, 0.f, 0.f, 0.f};

  for (int kt = 0; kt < 12; ++kt) {
    __syncthreads();
#pragma unroll
    for (int ci = 0; ci < 4; ++ci) {
      int idx = ci * 1024 + lane * 16;
      int rl = idx >> 7, col = idx & 127;
      int row = w * 32 + rl;
      int scol = col ^ ((row & 7) << 4);
      __builtin_amdgcn_global_load_lds(
          (const GAS*)(Xbb + (size_t)(m0 + row) * 1536 + kt * 128 + scol),
          (LAS*)(sA + w * 4096 + ci * 1024), 16, 0, 0);
      __builtin_amdgcn_global_load_lds(
          (const GAS*)(Wtb + (size_t)(n0 + row) * 1536 + kt * 128 + scol),
          (LAS*)(sB + w * 4096 + ci * 1024), 16, 0, 0);
    }
    __syncthreads();
    bf16x8 af[4][2], bfr[4][2];
#pragma unroll
    for (int ms = 0; ms < 4; ++ms) {
      int row = wm * 64 + ms * 16 + ln;
#pragma unroll
      for (int ks = 0; ks < 2; ++ks)
        af[ms][ks] = *(const bf16x8*)(sA + ((row * 128 + ks * 64 + g * 16) ^ ((row & 7) << 4)));
    }
#pragma unroll
    for (int c = 0; c < 4; ++c) {
      int row = wn * 64 + c * 16 + ln;
#pragma unroll
      for (int ks = 0; ks < 2; ++ks)
        bfr[c][ks] = *(const bf16x8*)(sB + ((row * 128 + ks * 64 + g * 16) ^ ((row & 7) << 4)));
    }
#pragma unroll
    for (int ms = 0; ms < 4; ++ms)
#pragma unroll
      for (int c = 0; c < 4; ++c) {
        acc[ms][c] = __builtin_amdgcn_mfma_f32_16x16x32_bf16(af[ms][0], bfr[c][0], acc[ms][c], 0, 0, 0);
        acc[ms][c] = __builtin_amdgcn_mfma_f32_16x16x32_bf16(af[ms][1], bfr[c][1], acc[ms][c], 0, 0, 0);
      }
  }
  float b4[4];
#pragma unroll
  for (int c = 0; c < 4; ++c) b4[c] = bias[hb * 64 + c * 16 + ln];
#pragma unroll
  for (int ms = 0; ms < 4; ++ms)
#pragma unroll
    for (int c = 0; c < 4; ++c)
#pragma unroll
      for (int jj = 0; jj < 4; ++jj) {
        int m = m0 + wm * 64 + ms * 16 + g * 4 + jj;
        int bb = m >> 10, s = m & 1023;
        float v = acc[ms][c][jj] + b4[c];
        Out[((size_t)(bb * 12 + hb) * 1024 + s) * 64 + c * 16 + ln] = f2bf(v);
      }
}

// ---------------- K3: V -> V^T  ([bh][s][d] -> [bh][d][s]) ---------------------------
__global__ __launch_bounds__(256) void vtrans_kernel(
    const unsigned short* __restrict__ Vb, unsigned short* __restrict__ Vtb)
{
  const int s0 = blockIdx.x * 256, bh = blockIdx.y, t = threadIdx.x;
  __shared__ __align__(16) unsigned short lds[256 * 64];
  const unsigned short* src = Vb + ((size_t)bh * 1024 + s0 + t) * 64;
#pragma unroll
  for (int gi = 0; gi < 8; ++gi) {
    uint4 v = *(const uint4*)(src + gi * 8);
    *(uint4*)((unsigned char*)lds + t * 128 + ((gi ^ (t & 7)) << 4)) = v;
  }
  __syncthreads();
  const int d = t >> 2, seg = t & 3;
  unsigned short* dst = Vtb + ((size_t)bh * 64 + d) * 1024 + s0 + seg * 64;
#pragma unroll
  for (int ck = 0; ck < 8; ++ck) {
    union { unsigned short u[8]; uint4 v; } pk;
#pragma unroll
    for (int e = 0; e < 8; ++e) {
      int sl = seg * 64 + ck * 8 + e;
      pk.u[e] = lds[sl * 64 + (((d >> 3) ^ (sl & 7)) << 3) + (d & 7)];
    }
    *(uint4*)(dst + ck * 8) = pk.v;
  }
}

// ---------------- K4: fused attention (split-r 2-way, XCD-grouped heads) -------------
// LDS: sK 8192 | sV 8192 | Ht [128][68] 17408 | per-wave Gt[80][20] / P overlay 4x3264
__global__ __launch_bounds__(256, 2) void attn_kernel(
    const float* __restrict__ amask, const _Float16* __restrict__ Lm,
    const unsigned short* __restrict__ Qb, const unsigned short* __restrict__ Kb,
    const unsigned short* __restrict__ Vtb, const unsigned short* __restrict__ Eb,
    float* __restrict__ pctx, float* __restrict__ pm)
{
  // flat 1536-block grid; dispatch round-robins XCDs, so chunk-remap puts all 12
  // heads of one (b,lb,half) group on the same XCD -> Lm/K/V reuse hits its L2
  const int orig = blockIdx.x;
  const int wg = (orig & 7) * 192 + (orig >> 3);
  const int h = wg % 12;
  const int grp = wg / 12;  // 0..127
  const int half = grp & 1, lb = (grp >> 1) & 15, b = grp >> 5;
  const int bh = b * 12 + h, l0 = lb * 64;
  const int t = threadIdx.x, w = t >> 6, lane = t & 63, g = lane >> 4, ln = lane & 15;
  __shared__ __align__(16) unsigned char smem[46848];
  unsigned char* sK = smem;                                  // [64 r][64 k] swz
  unsigned char* sV = smem + 8192;                           // [64 d][64 r] swz
  unsigned short* Ht = (unsigned short*)(smem + 16384);      // [128 j][68 r-cols]
  unsigned short* Gtw = (unsigned short*)(smem + 33792 + w * 3264);  // [80 jl][20]
  unsigned char* Pw = (unsigned char*)Gtw;                   // overlay [16 l][64 r] swz

  const unsigned short* Qrow = Qb + ((size_t)bh * 1024 + l0 + w * 16 + ln) * 64;
  const bf16x8 qa0 = *(const bf16x8*)(Qrow + g * 8);
  const bf16x8 qa1 = *(const bf16x8*)(Qrow + 32 + g * 8);

  f32x4 ctx[4];
#pragma unroll
  for (int c = 0; c < 4; ++c) ctx[c] = f32x4{0.f, 0.f, 0.f, 0.f};
  float mrun[4] = {-1e30f, -1e30f, -1e30f, -1e30f};
  float sig[4] = {0.f, 0.f, 0.f, 0.f};

  const unsigned char* Kbase = (const unsigned char*)(Kb + (size_t)bh * 65536);
  const unsigned char* Vbase = (const unsigned char*)(Vtb + (size_t)bh * 65536);
  const int itBeg = half * 8, itEnd = itBeg + 8;

  const int sp = t * 16, srow = sp >> 7, scol = sp & 127;  // srow 0..31
  uint4 kp[2], vp[2];
#pragma unroll
  for (int i = 0; i < 2; ++i) {
    kp[i] = *(const uint4*)(Kbase + (size_t)(itBeg * 64 + srow + i * 32) * 128 + scol);
    vp[i] = *(const uint4*)(Vbase + (size_t)(srow + i * 32) * 2048 + itBeg * 128 + scol);
  }

  for (int it = itBeg; it < itEnd; ++it) {
    const int r0 = it * 64;
    __syncthreads();  // prev-iter readers of sK/sV done
    // stage K,V tiles (coalesced regs -> swizzled LDS)
#pragma unroll
    for (int i = 0; i < 2; ++i) {
      int p = i * 4096 + sp, row = p >> 7;
      int ad = p ^ ((row & 7) << 4);
      *(uint4*)(sK + ad) = kp[i];
      *(uint4*)(sV + ad) = vp[i];
    }
    // prefetch next K,V tiles (hidden under this whole iteration)
    if (it + 1 < itEnd) {
#pragma unroll
      for (int i = 0; i < 2; ++i) {
        kp[i] = *(const uint4*)(Kbase + (size_t)(r0 + 64 + srow + i * 32) * 128 + scol);
        vp[i] = *(const uint4*)(Vbase + (size_t)(srow + i * 32) * 2048 + (r0 + 64) * 2 + scol);
      }
    }
    // prefetch log2-mask (fp16) + amask
    float lmf[4][4];
    const _Float16* lrow = Lm + (size_t)b * 1048576 + (size_t)(l0 + w * 16 + g * 4) * 1024 + r0;
#pragma unroll
    for (int jj = 0; jj < 4; ++jj)
#pragma unroll
      for (int ct = 0; ct < 4; ++ct)
        lmf[ct][jj] = (float)lrow[(size_t)jj * 1024 + ct * 16 + ln];
    float am4[4];
#pragma unroll
    for (int ct = 0; ct < 4; ++ct)
      am4[ct] = amask[b * 1024 + r0 + ct * 16 + ln] * 1.4426950408889634f;

    // ---- G phase (wave-private): G[l][j] = q[l].E[D0+j], j-window [w16, w16+80)
    const int D0 = l0 - r0 + 960;
#pragma unroll
    for (int cc = 0; cc < 5; ++cc) {
      int c = w + cc;
      const unsigned short* Erow = Eb + (size_t)(D0 + c * 16 + ln) * 64;
      bf16x8 e0 = *(const bf16x8*)(Erow + g * 8);
      bf16x8 e1 = *(const bf16x8*)(Erow + 32 + g * 8);
      f32x4 ga = f32x4{0.f, 0.f, 0.f, 0.f};
      ga = __builtin_amdgcn_mfma_f32_16x16x32_bf16(qa0, e0, ga, 0, 0, 0);
      ga = __builtin_amdgcn_mfma_f32_16x16x32_bf16(qa1, e1, ga, 0, 0, 0);
      ushort4 pk = {f2bf(ga[0]), f2bf(ga[1]), f2bf(ga[2]), f2bf(ga[3])};
      *(ushort4*)(Gtw + (cc * 16 + ln) * 20 + g * 4) = pk;
    }
    __syncthreads();  // sK/sV staged + visible
    // QK fragments + H A-operand
    bf16x8 kb[4][2];
#pragma unroll
    for (int c = 0; c < 4; ++c)
#pragma unroll
      for (int ks = 0; ks < 2; ++ks) {
        int row = c * 16 + ln;
        kb[c][ks] = *(const bf16x8*)(sK + ((row * 128 + ks * 64 + g * 16) ^ ((row & 7) << 4)));
      }
    bf16x8 ha0, ha1;
    {
      int row = w * 16 + ln;
      ha0 = *(const bf16x8*)(sK + ((row * 128 + g * 16) ^ ((row & 7) << 4)));
      ha1 = *(const bf16x8*)(sK + ((row * 128 + 64 + g * 16) ^ ((row & 7) << 4)));
    }
    // ---- H phase: H[r][j] = k[r].E[D0+j]; own r-rows, j-tiles c in [3-w, 7-w]
#pragma unroll
    for (int cc = 0; cc < 5; ++cc) {
      int c = 3 - w + cc;
      const unsigned short* Erow = Eb + (size_t)(D0 + c * 16 + ln) * 64;
      bf16x8 e0 = *(const bf16x8*)(Erow + g * 8);
      bf16x8 e1 = *(const bf16x8*)(Erow + 32 + g * 8);
      f32x4 hac = f32x4{0.f, 0.f, 0.f, 0.f};
      hac = __builtin_amdgcn_mfma_f32_16x16x32_bf16(ha0, e0, hac, 0, 0, 0);
      hac = __builtin_amdgcn_mfma_f32_16x16x32_bf16(ha1, e1, hac, 0, 0, 0);
      ushort4 pk = {f2bf(hac[0]), f2bf(hac[1]), f2bf(hac[2]), f2bf(hac[3])};
      *(ushort4*)(Ht + (size_t)(c * 16 + ln) * 68 + w * 16 + g * 4) = pk;
    }
    __syncthreads();  // Ht visible
    // ---- bias gather into C, then QK^T accumulates on top
    f32x4 sacc[4];
#pragma unroll
    for (int ct = 0; ct < 4; ++ct) {
      int rlb = ct * 16 + ln;
      f32x4 si;
#pragma unroll
      for (int jj = 0; jj < 4; ++jj) {
        int lloc = g * 4 + jj;
        int j = w * 16 + lloc - rlb + 63;
        si[jj] = bf2f(Gtw[(lloc - rlb + 63) * 20 + lloc]) + bf2f(Ht[(size_t)j * 68 + rlb]);
      }
      sacc[ct] = si;
      sacc[ct] = __builtin_amdgcn_mfma_f32_16x16x32_bf16(qa0, kb[ct][0], sacc[ct], 0, 0, 0);
      sacc[ct] = __builtin_amdgcn_mfma_f32_16x16x32_bf16(qa1, kb[ct][1], sacc[ct], 0, 0, 0);
    }
    // ---- online softmax, fully additive in log2 domain
    float sv[4][4], rmax[4];
#pragma unroll
    for (int jj = 0; jj < 4; ++jj) {
#pragma unroll
      for (int ct = 0; ct < 4; ++ct)
        sv[ct][jj] = sacc[ct][jj] * 0.1803368801f + am4[ct] + lmf[ct][jj];
      float rv = fmaxf(fmaxf(sv[0][jj], sv[1][jj]), fmaxf(sv[2][jj], sv[3][jj]));
#pragma unroll
      for (int mm = 1; mm < 16; mm <<= 1) rv = fmaxf(rv, __shfl_xor(rv, mm));
      rmax[jj] = rv;
    }
    float sf[4], mnew[4];
#pragma unroll
    for (int jj = 0; jj < 4; ++jj) {
      mnew[jj] = fmaxf(mrun[jj], rmax[jj]);
      sf[jj] = __builtin_amdgcn_exp2f(mrun[jj] - mnew[jj]);
      mrun[jj] = mnew[jj];
    }
    float rs[4] = {0.f, 0.f, 0.f, 0.f};
    unsigned short pb[4][4];
#pragma unroll
    for (int ct = 0; ct < 4; ++ct)
#pragma unroll
      for (int jj = 0; jj < 4; ++jj) {
        float p = __builtin_amdgcn_exp2f(sv[ct][jj] - mnew[jj]);
        rs[jj] += p;
        pb[ct][jj] = f2bf(p);
      }
#pragma unroll
    for (int jj = 0; jj < 4; ++jj) {
      float rv = rs[jj];
#pragma unroll
      for (int mm = 1; mm < 16; mm <<= 1) rv += __shfl_xor(rv, mm);
      sig[jj] = sig[jj] * sf[jj] + rv;
    }
#pragma unroll
    for (int c = 0; c < 4; ++c)
#pragma unroll
      for (int jj = 0; jj < 4; ++jj) ctx[c][jj] *= sf[jj];
    // ---- P -> wave-private LDS (overlays Gt; safe by in-wave data order)
#pragma unroll
    for (int ct = 0; ct < 4; ++ct)
#pragma unroll
      for (int jj = 0; jj < 4; ++jj) {
        int lp = g * 4 + jj;
        *(unsigned short*)(Pw + ((lp * 128 + (ct * 16 + ln) * 2) ^ ((lp & 7) << 4))) = pb[ct][jj];
      }
    bf16x8 pa0, pa1;
    {
      int lr = ln;
      pa0 = *(const bf16x8*)(Pw + ((lr * 128 + g * 16) ^ ((lr & 7) << 4)));
      pa1 = *(const bf16x8*)(Pw + ((lr * 128 + 64 + g * 16) ^ ((lr & 7) << 4)));
    }
    // ---- PV from LDS-staged V^T
#pragma unroll
    for (int cd = 0; cd < 4; ++cd) {
      int row = cd * 16 + ln;
      bf16x8 v0 = *(const bf16x8*)(sV + ((row * 128 + g * 16) ^ ((row & 7) << 4)));
      bf16x8 v1 = *(const bf16x8*)(sV + ((row * 128 + 64 + g * 16) ^ ((row & 7) << 4)));
      ctx[cd] = __builtin_amdgcn_mfma_f32_16x16x32_bf16(pa0, v0, ctx[cd], 0, 0, 0);
      ctx[cd] = __builtin_amdgcn_mfma_f32_16x16x32_bf16(pa1, v1, ctx[cd], 0, 0, 0);
    }
  }
  // ---- write partials
  const size_t rowb = (size_t)(half * 48 + bh) * 1024 + l0 + w * 16;
#pragma unroll
  for (int cd = 0; cd < 4; ++cd)
#pragma unroll
    for (int jj = 0; jj < 4; ++jj)
      pctx[(rowb + g * 4 + jj) * 64 + cd * 16 + ln] = ctx[cd][jj];
  if (ln == 0) {
#pragma unroll
    for (int jj = 0; jj < 4; ++jj) {
      size_t rr = rowb + g * 4 + jj;
      pm[rr * 2] = mrun[jj];
      pm[rr * 2 + 1] = sig[jj];
    }
  }
}

// ---------------- K5: combine the two r-halves ---------------------------------------
__global__ __launch_bounds__(256) void combine_kernel(
    const float* __restrict__ pctx, const float* __restrict__ pm,
    float* __restrict__ out)
{
  int tid = blockIdx.x * 256 + threadIdx.x;
  int row = tid >> 4, dq = (tid & 15) * 4;
  int bh = row >> 10, l = row & 1023, b = bh / 12, hh = bh % 12;
  float m0 = pm[(size_t)row * 2], s0 = pm[(size_t)row * 2 + 1];
  float m1 = pm[(size_t)(49152 + row) * 2], s1 = pm[(size_t)(49152 + row) * 2 + 1];
  float M = fmaxf(m0, m1);
  float w0 = __builtin_amdgcn_exp2f(m0 - M), w1 = __builtin_amdgcn_exp2f(m1 - M);
  float inv = 1.f / (s0 * w0 + s1 * w1);
  float4 c0 = *(const float4*)(pctx + (size_t)row * 64 + dq);
  float4 c1 = *(const float4*)(pctx + (size_t)(49152 + row) * 64 + dq);
  float4 o;
  o.x = (c0.x * w0 + c1.x * w1) * inv;
  o.y = (c0.y * w0 + c1.y * w1) * inv;
  o.z = (c0.z * w0 + c1.z * w1) * inv;
  o.w = (c0.w * w0 + c1.w * w1) * inv;
  *(float4*)(out + (size_t)(b * 1024 + l) * 768 + hh * 64 + dq) = o;
}

extern "C" void kernel_launch(void* const* d_in, const int* in_sizes, int n_in,
                              void* d_out, int out_size, void* d_ws, size_t ws_size,
                              hipStream_t stream) {
  const float* hs    = (const float*)d_in[0];
  const float* amask = (const float*)d_in[1];
  const float* rmask = (const float*)d_in[2];
  const float* Wq    = (const float*)d_in[3];
  const float* bq    = (const float*)d_in[4];
  const float* Wk    = (const float*)d_in[5];
  const float* bk    = (const float*)d_in[6];
  const float* Wv    = (const float*)d_in[7];
  const float* bv    = (const float*)d_in[8];
  const float* de    = (const float*)d_in[9];
  unsigned char* ws = (unsigned char*)d_ws;
  // pctx (25 MB) overlays Xb/Wt/Vb, which are dead before attn writes it.
  float*          pctx = (float*)(ws + 0);                 // 25165824 B
  unsigned short* Xb   = (unsigned short*)(ws + 0);        //  6291456 B (dead after proj)
  unsigned short* Wt   = (unsigned short*)(ws + 6291456);  //  3538944 B (dead after proj)
  unsigned short* Vb   = (unsigned short*)(ws + 9830400);  //  6291456 B (dead after vtrans)
  unsigned short* Eb   = (unsigned short*)(ws + 25165824); //   262144 B
  unsigned short* Qb   = (unsigned short*)(ws + 25427968); //  6291456 B
  unsigned short* Kb   = (unsigned short*)(ws + 31719424); //  6291456 B
  unsigned short* Vtb  = (unsigned short*)(ws + 38010880); //  6291456 B
  _Float16*       Lm   = (_Float16*)(ws + 44302336);       //  8388608 B
  float*          pm   = (float*)(ws + 52690944);          //   786432 B (total 53.5 MB)
  float* out = (float*)d_out;

  hipLaunchKernelGGL(prep_kernel, dim3(4080), dim3(256), 0, stream,
                     hs, Wq, Wk, Wv, de, rmask, Xb, Wt, Eb, Lm);
  hipLaunchKernelGGL(proj_kernel, dim3(32, 18), dim3(256), 0, stream,
                     Xb, Wt, bq, bk, bv, Qb, Kb, Vb);
  hipLaunchKernelGGL(vtrans_kernel, dim3(4, 48), dim3(256), 0, stream, Vb, Vtb);
  hipLaunchKernelGGL(attn_kernel, dim3(1536), dim3(256), 0, stream,
                     amask, Lm, Qb, Kb, Vtb, Eb, pctx, pm);
  hipLaunchKernelGGL(combine_kernel, dim3(3072), dim3(256), 0, stream, pctx, pm, out);
}